// Round 1
// baseline (320.413 us; speedup 1.0000x reference)
//
#include <hip/hip_runtime.h>
#include <stdint.h>

#define NEG_INF -1e9f

typedef float f32x4 __attribute__((ext_vector_type(4)));
typedef short bf16x8 __attribute__((ext_vector_type(8)));
typedef unsigned short ushort8 __attribute__((ext_vector_type(8)));

// round-to-nearest (away) f32 -> bf16
__device__ __forceinline__ unsigned short f2bf(float x) {
  union { float f; uint32_t u; } c; c.f = x;
  return (unsigned short)((c.u + 0x8000u) >> 16);
}

// ---------------- prep: W_enc f32 -> bf16, tile-packed [nt][kt][128][32] ----------------
__global__ void prep_w_k(const float* __restrict__ W, unsigned short* __restrict__ Wt) {
  int t = blockIdx.x * 256 + threadIdx.x;      // 131072 threads, 8 elems each
  int d  = t >> 7;
  int e0 = (t & 127) << 3;
  const float* src = W + ((size_t)d << 10) + e0;
  f32x4 f0 = *(const f32x4*)src;
  f32x4 f1 = *(const f32x4*)(src + 4);
  ushort8 u;
  u[0]=f2bf(f0[0]); u[1]=f2bf(f0[1]); u[2]=f2bf(f0[2]); u[3]=f2bf(f0[3]);
  u[4]=f2bf(f1[0]); u[5]=f2bf(f1[1]); u[6]=f2bf(f1[2]); u[7]=f2bf(f1[3]);
  int nt = d >> 7, r = d & 127, kt = e0 >> 5, c = e0 & 31;
  *(ushort8*)(Wt + (((size_t)(nt * 32 + kt)) << 12) + r * 32 + c) = u;
}

// ---------------- prep: dh = dec_hidden @ W_dec^T  (f32 VALU, tiny) ----------------
__global__ void prep_dh_k(const float* __restrict__ dec, const float* __restrict__ Wd,
                          float* __restrict__ dh) {
  __shared__ float sdec[1024];
  int b = blockIdx.x >> 2;                      // 4 blocks per batch row
  for (int i = threadIdx.x; i < 1024; i += 256) sdec[i] = dec[(b << 10) + i];
  __syncthreads();
  int d = ((blockIdx.x & 3) << 8) + threadIdx.x;
  const float* wr = Wd + ((size_t)d << 10);
  float a = 0.f;
  for (int k = 0; k < 1024; k += 4) {
    f32x4 wv = *(const f32x4*)(wr + k);
    f32x4 xv = *(const f32x4*)(&sdec[k]);
    a += wv[0]*xv[0] + wv[1]*xv[1] + wv[2]*xv[2] + wv[3]*xv[3];
  }
  dh[(b << 10) + d] = a;
}

// ---------------- main fused GEMM: partial scores[nt][row] = sum_d v*tanh(dh+eh) ----------------
__global__ __launch_bounds__(256) void score_gemm_k(
    const float* __restrict__ enc, const unsigned short* __restrict__ Wt,
    const float* __restrict__ dh, const float* __restrict__ v,
    float* __restrict__ pscores)
{
  // XCD swizzle: 8 consecutive dispatch ids (same XCD, adjacent in time) share one A-tile (mt)
  int xcd = blockIdx.x & 7;
  int pos = blockIdx.x >> 3;
  int L   = xcd * 512 + pos;       // 4096 blocks, bijective
  int mt  = L >> 3;
  int nt  = L & 7;
  int m0 = mt << 7, n0 = nt << 7;
  int b  = m0 >> 11;               // 2048 rows per batch; 128 | 2048 so b uniform per block

  __shared__ __align__(16) unsigned short As[2][128][32];
  __shared__ __align__(16) unsigned short Bs[2][128][32];
  __shared__ float sc[128][2];

  int tid  = threadIdx.x;
  int lane = tid & 63;
  int wave = tid >> 6;
  int wm = wave >> 1, wn = wave & 1;

  f32x4 acc[4][4];
  #pragma unroll
  for (int i = 0; i < 4; ++i)
    #pragma unroll
    for (int j = 0; j < 4; ++j)
      acc[i][j] = (f32x4){0.f, 0.f, 0.f, 0.f};

  auto stage = [&](int bi, int kt) {
    int k0 = kt << 5;
    // A: reg-stage f32 -> bf16 (128x32)
    #pragma unroll
    for (int j = 0; j < 2; ++j) {
      int r = (tid >> 2) + j * 64;
      int c = (tid & 3) << 3;
      const float* src = enc + (((size_t)(m0 + r)) << 10) + k0 + c;
      f32x4 f0 = *(const f32x4*)src;
      f32x4 f1 = *(const f32x4*)(src + 4);
      ushort8 u;
      u[0]=f2bf(f0[0]); u[1]=f2bf(f0[1]); u[2]=f2bf(f0[2]); u[3]=f2bf(f0[3]);
      u[4]=f2bf(f1[0]); u[5]=f2bf(f1[1]); u[6]=f2bf(f1[2]); u[7]=f2bf(f1[3]);
      *(ushort8*)&As[bi][r][c] = u;
    }
    // B: async global->LDS, pre-packed linear tile (8 KB)
    const unsigned short* tbase = Wt + (((size_t)(nt * 32 + kt)) << 12);
    #pragma unroll
    for (int j = 0; j < 2; ++j) {
      int chunk = wave * 2 + j;
      const unsigned short* g = tbase + chunk * 512 + lane * 8;
      void* l = (void*)(&Bs[bi][0][0] + chunk * 512);
      __builtin_amdgcn_global_load_lds((__attribute__((address_space(1))) void*)(void*)g,
                                       (__attribute__((address_space(3))) void*)l, 16, 0, 0);
    }
  };

  auto compute = [&](int bi) {
    bf16x8 a[4], bb[4];
    #pragma unroll
    for (int i = 0; i < 4; ++i)
      a[i] = *(const bf16x8*)&As[bi][wm * 64 + i * 16 + (lane & 15)][(lane >> 4) << 3];
    #pragma unroll
    for (int j = 0; j < 4; ++j)
      bb[j] = *(const bf16x8*)&Bs[bi][wn * 64 + j * 16 + (lane & 15)][(lane >> 4) << 3];
    #pragma unroll
    for (int i = 0; i < 4; ++i)
      #pragma unroll
      for (int j = 0; j < 4; ++j)
        acc[i][j] = __builtin_amdgcn_mfma_f32_16x16x32_bf16(a[i], bb[j], acc[i][j], 0, 0, 0);
  };

  stage(0, 0);
  __syncthreads();
  int bi = 0;
  for (int kt = 0; kt < 31; ++kt) {
    stage(bi ^ 1, kt + 1);
    compute(bi);
    __syncthreads();
    bi ^= 1;
  }
  compute(bi);

  // epilogue: p[row] += sum_cols v[d] * tanh(acc + dh[b][d])
  int cb = n0 + wn * 64 + (lane & 15);
  float vv[4], dd[4];
  #pragma unroll
  for (int j = 0; j < 4; ++j) {
    int dcol = cb + j * 16;
    vv[j] = v[dcol];
    dd[j] = dh[(b << 10) + dcol];
  }
  #pragma unroll
  for (int i = 0; i < 4; ++i) {
    #pragma unroll
    for (int r = 0; r < 4; ++r) {
      float p = 0.f;
      #pragma unroll
      for (int j = 0; j < 4; ++j) {
        float x = acc[i][j][r] + dd[j];
        float e = __expf(2.0f * x);                 // tanh(x) = 1 - 2/(e^{2x}+1)
        float t = 1.0f - __fdividef(2.0f, e + 1.0f);
        p += vv[j] * t;
      }
      p += __shfl_xor(p, 1); p += __shfl_xor(p, 2);
      p += __shfl_xor(p, 4); p += __shfl_xor(p, 8);
      if ((lane & 15) == 0)
        sc[wm * 64 + i * 16 + ((lane >> 4) << 2) + r][wn] = p;
    }
  }
  __syncthreads();
  if (tid < 128)
    pscores[((size_t)nt << 16) + m0 + tid] = sc[tid][0] + sc[tid][1];
}

// ---------------- softmax over S with mask; writes weights ----------------
__global__ void softmax_k(const float* __restrict__ ps, const int* __restrict__ mask,
                          float* __restrict__ wout) {
  int b = blockIdx.x;
  int tid = threadIdx.x;
  float val[8];
  float m = NEG_INF;
  #pragma unroll
  for (int ii = 0; ii < 8; ++ii) {
    int s = tid + ii * 256;
    size_t row = ((size_t)b << 11) + s;
    float sum = 0.f;
    #pragma unroll
    for (int nt = 0; nt < 8; ++nt) sum += ps[((size_t)nt << 16) + row];
    if (mask[row] == 0) sum = NEG_INF;
    val[ii] = sum;
    m = fmaxf(m, sum);
  }
  #pragma unroll
  for (int off = 1; off < 64; off <<= 1) m = fmaxf(m, __shfl_xor(m, off));
  __shared__ float r1[4], r2[4];
  if ((tid & 63) == 0) r1[tid >> 6] = m;
  __syncthreads();
  m = fmaxf(fmaxf(r1[0], r1[1]), fmaxf(r1[2], r1[3]));
  float ssum = 0.f;
  #pragma unroll
  for (int ii = 0; ii < 8; ++ii) { val[ii] = __expf(val[ii] - m); ssum += val[ii]; }
  #pragma unroll
  for (int off = 1; off < 64; off <<= 1) ssum += __shfl_xor(ssum, off);
  if ((tid & 63) == 0) r2[tid >> 6] = ssum;
  __syncthreads();
  ssum = r2[0] + r2[1] + r2[2] + r2[3];
  float inv = 1.0f / ssum;
  #pragma unroll
  for (int ii = 0; ii < 8; ++ii)
    wout[((size_t)b << 11) + tid + ii * 256] = val[ii] * inv;
}

// ---------------- context partials: cp[b][ch][e] = sum_{s in chunk} w*enc ----------------
__global__ void ctx_part_k(const float* __restrict__ enc, const float* __restrict__ w,
                           float* __restrict__ cp) {
  int bb = blockIdx.x;                 // 512 = 32 b * 16 chunks(128 s)
  int b = bb >> 4, ch = bb & 15;
  __shared__ float sw[128];
  if (threadIdx.x < 128) sw[threadIdx.x] = w[((size_t)b << 11) + (ch << 7) + threadIdx.x];
  __syncthreads();
  int e0 = threadIdx.x << 2;
  const float* base = enc + ((((size_t)b << 11) + (ch << 7)) << 10) + e0;
  f32x4 acc = {0.f, 0.f, 0.f, 0.f};
  for (int s = 0; s < 128; ++s) {
    f32x4 x = *(const f32x4*)(base + ((size_t)s << 10));
    float wv = sw[s];
    acc[0] += wv * x[0]; acc[1] += wv * x[1]; acc[2] += wv * x[2]; acc[3] += wv * x[3];
  }
  *(f32x4*)(cp + ((size_t)bb << 10) + e0) = acc;
}

__global__ void ctx_red_k(const float* __restrict__ cp, float* __restrict__ out) {
  int t = blockIdx.x * 256 + threadIdx.x;   // 32768
  int b = t >> 10, e = t & 1023;
  float a = 0.f;
  #pragma unroll
  for (int ch = 0; ch < 16; ++ch) a += cp[(((size_t)(b * 16 + ch)) << 10) + e];
  out[t] = a;
}

extern "C" void kernel_launch(void* const* d_in, const int* in_sizes, int n_in,
                              void* d_out, int out_size, void* d_ws, size_t ws_size,
                              hipStream_t stream) {
  const float* dec  = (const float*)d_in[0];
  const float* enc  = (const float*)d_in[1];
  const int*   mask = (const int*)d_in[2];
  const float* Wenc = (const float*)d_in[3];
  const float* Wdec = (const float*)d_in[4];
  const float* v    = (const float*)d_in[5];
  float* out_ctx = (float*)d_out;                 // [32][1024]
  float* out_w   = (float*)d_out + 32768;         // [32][2048]

  char* ws = (char*)d_ws;
  unsigned short* Wt = (unsigned short*)ws;                           // 2 MB  tile-packed bf16 W_enc
  float* dh      = (float*)(ws + (2u << 20));                         // 128 KB
  float* pscores = (float*)(ws + (2u << 20) + (128u << 10));          // 2 MB  [8][65536]
  float* cp      = (float*)(ws + (4u << 20) + (128u << 10));          // 2 MB  [512][1024]

  hipLaunchKernelGGL(prep_w_k,     dim3(512),  dim3(256), 0, stream, Wenc, Wt);
  hipLaunchKernelGGL(prep_dh_k,    dim3(128),  dim3(256), 0, stream, dec, Wdec, dh);
  hipLaunchKernelGGL(score_gemm_k, dim3(4096), dim3(256), 0, stream, enc, Wt, dh, v, pscores);
  hipLaunchKernelGGL(softmax_k,    dim3(32),   dim3(256), 0, stream, pscores, mask, out_w);
  hipLaunchKernelGGL(ctx_part_k,   dim3(512),  dim3(256), 0, stream, enc, out_w, cp);
  hipLaunchKernelGGL(ctx_red_k,    dim3(128),  dim3(256), 0, stream, cp, out_ctx);
}

// Round 2
// 228.251 us; speedup vs baseline: 1.4038x; 1.4038x over previous
//
#include <hip/hip_runtime.h>
#include <stdint.h>

#define NEG_INF -1e9f

typedef float f32x4 __attribute__((ext_vector_type(4)));
typedef short bf16x8 __attribute__((ext_vector_type(8)));
typedef unsigned short ushort8 __attribute__((ext_vector_type(8)));

// round-to-nearest (away) f32 -> bf16
__device__ __forceinline__ unsigned short f2bf(float x) {
  union { float f; uint32_t u; } c; c.f = x;
  return (unsigned short)((c.u + 0x8000u) >> 16);
}

// ---------------- prep: W_enc f32 -> bf16, tile-packed [nt][kt][128][32] ----------------
__global__ void prep_w_k(const float* __restrict__ W, unsigned short* __restrict__ Wt) {
  int t = blockIdx.x * 256 + threadIdx.x;      // 131072 threads, 8 elems each
  int d  = t >> 7;
  int e0 = (t & 127) << 3;
  const float* src = W + ((size_t)d << 10) + e0;
  f32x4 f0 = *(const f32x4*)src;
  f32x4 f1 = *(const f32x4*)(src + 4);
  ushort8 u;
  u[0]=f2bf(f0[0]); u[1]=f2bf(f0[1]); u[2]=f2bf(f0[2]); u[3]=f2bf(f0[3]);
  u[4]=f2bf(f1[0]); u[5]=f2bf(f1[1]); u[6]=f2bf(f1[2]); u[7]=f2bf(f1[3]);
  int nt = d >> 7, r = d & 127, kt = e0 >> 5, c = e0 & 31;
  *(ushort8*)(Wt + (((size_t)(nt * 32 + kt)) << 12) + r * 32 + c) = u;
}

// ---------------- prep: dh = dec_hidden @ W_dec^T  (f32 VALU, tiny) ----------------
__global__ void prep_dh_k(const float* __restrict__ dec, const float* __restrict__ Wd,
                          float* __restrict__ dh) {
  __shared__ float sdec[1024];
  int b = blockIdx.x >> 2;                      // 4 blocks per batch row
  for (int i = threadIdx.x; i < 1024; i += 256) sdec[i] = dec[(b << 10) + i];
  __syncthreads();
  int d = ((blockIdx.x & 3) << 8) + threadIdx.x;
  const float* wr = Wd + ((size_t)d << 10);
  float a = 0.f;
  for (int k = 0; k < 1024; k += 4) {
    f32x4 wv = *(const f32x4*)(wr + k);
    f32x4 xv = *(const f32x4*)(&sdec[k]);
    a += wv[0]*xv[0] + wv[1]*xv[1] + wv[2]*xv[2] + wv[3]*xv[3];
  }
  dh[(b << 10) + d] = a;
}

// ---------------- compaction: per-batch list of unmasked rows + count; zero out_w ----------------
__global__ void compact_k(const int* __restrict__ mask, int* __restrict__ rows,
                          int* __restrict__ cnt, float* __restrict__ wout) {
  int b = blockIdx.x, tid = threadIdx.x;
  int lane = tid & 63, wv = tid >> 6;
  int mloc[8]; int c = 0;
  #pragma unroll
  for (int ii = 0; ii < 8; ++ii) {
    int s = tid * 8 + ii;
    int m = mask[(b << 11) + s];
    mloc[ii] = m; c += m;
    wout[(b << 11) + s] = 0.f;          // masked positions must be exactly 0 every call
  }
  int inc = c;
  #pragma unroll
  for (int off = 1; off < 64; off <<= 1) {
    int nn = __shfl_up(inc, off);
    if (lane >= off) inc += nn;
  }
  __shared__ int wsum[4];
  if (lane == 63) wsum[wv] = inc;
  __syncthreads();
  int base = 0;
  for (int w = 0; w < wv; ++w) base += wsum[w];
  int idx = base + inc - c;             // exclusive prefix for this thread
  #pragma unroll
  for (int ii = 0; ii < 8; ++ii) {
    if (mloc[ii]) { rows[(b << 11) + idx] = tid * 8 + ii; ++idx; }
  }
  if (tid == 0) cnt[b] = wsum[0] + wsum[1] + wsum[2] + wsum[3];
}

// ---------------- pack: gather unmasked enc rows -> bf16 tiles [b][mt][kt][128][32] ----------------
__global__ void pack_k(const float* __restrict__ enc, const int* __restrict__ rows,
                       const int* __restrict__ cnt, unsigned short* __restrict__ encP) {
  int b = blockIdx.x >> 4, mt = blockIdx.x & 15;
  int n = cnt[b];
  if (mt * 128 >= n) return;
  __shared__ int sr[128];
  if (threadIdx.x < 128) {
    int i = mt * 128 + threadIdx.x; if (i >= n) i = n - 1;   // clamp pad rows (always finite)
    sr[threadIdx.x] = rows[(b << 11) + i];
  }
  __syncthreads();
  unsigned short* dst = encP + ((size_t)(b * 16 + mt) << 17);
  for (int it = 0; it < 64; ++it) {
    int chunk = it * 256 + threadIdx.x;
    int ir = chunk >> 7;
    int e0 = (chunk & 127) << 3;
    const float* src = enc + (((size_t)(b << 11) + sr[ir]) << 10) + e0;
    f32x4 f0 = *(const f32x4*)src;
    f32x4 f1 = *(const f32x4*)(src + 4);
    ushort8 u;
    u[0]=f2bf(f0[0]); u[1]=f2bf(f0[1]); u[2]=f2bf(f0[2]); u[3]=f2bf(f0[3]);
    u[4]=f2bf(f1[0]); u[5]=f2bf(f1[1]); u[6]=f2bf(f1[2]); u[7]=f2bf(f1[3]);
    int kt = e0 >> 5, cc = e0 & 31;
    *(ushort8*)(dst + kt * 4096 + ir * 32 + cc) = u;
  }
}

// ---------------- main fused GEMM over compacted rows ----------------
template<bool PACKED>
__global__ __launch_bounds__(256) void score2_k(
    const float* __restrict__ enc, const unsigned short* __restrict__ encP,
    const unsigned short* __restrict__ Wt, const float* __restrict__ dh,
    const float* __restrict__ v, const int* __restrict__ rows,
    const int* __restrict__ cnt, float* __restrict__ pscores)
{
  // XCD swizzle: 8 consecutive dispatch ids share one A-tile
  int xcd = blockIdx.x & 7;
  int pos = blockIdx.x >> 3;
  int L   = xcd * 512 + pos;        // bijective, 4096 = 8*512
  int bt  = L >> 3, nt = L & 7;
  int b   = bt >> 4, mt = bt & 15;
  int n0  = nt << 7;
  int cb_cnt = cnt[b];
  if (mt * 128 >= cb_cnt) return;   // uniform early exit (dead tile)

  __shared__ __align__(16) unsigned short As[2][128][32];
  __shared__ __align__(16) unsigned short Bs[2][128][32];
  __shared__ float sc[128][2];
  __shared__ int srow[128];

  int tid  = threadIdx.x;
  int lane = tid & 63;
  int wave = tid >> 6;
  int wm = wave >> 1, wn = wave & 1;

  const float* agp0 = nullptr;
  const float* agp1 = nullptr;
  if constexpr (!PACKED) {
    if (tid < 128) {
      int i = mt * 128 + tid; if (i >= cb_cnt) i = cb_cnt - 1;
      srow[tid] = rows[(b << 11) + i];
    }
    __syncthreads();
    int r0 = tid >> 2, c = (tid & 3) << 3;
    agp0 = enc + (((size_t)(b << 11) + srow[r0])      << 10) + c;
    agp1 = enc + (((size_t)(b << 11) + srow[r0 + 64]) << 10) + c;
  }
  const unsigned short* atile = nullptr;
  if constexpr (PACKED) atile = encP + ((size_t)(b * 16 + mt) << 17);

  f32x4 acc[4][4];
  #pragma unroll
  for (int i = 0; i < 4; ++i)
    #pragma unroll
    for (int j = 0; j < 4; ++j)
      acc[i][j] = (f32x4){0.f, 0.f, 0.f, 0.f};

  auto stage = [&](int bi, int kt) {
    if constexpr (PACKED) {
      const unsigned short* ta = atile + ((size_t)kt << 12);
      #pragma unroll
      for (int j = 0; j < 2; ++j) {
        int chunk = wave * 2 + j;
        const unsigned short* g = ta + chunk * 512 + lane * 8;
        void* l = (void*)(&As[bi][0][0] + chunk * 512);
        __builtin_amdgcn_global_load_lds((__attribute__((address_space(1))) void*)(void*)g,
                                         (__attribute__((address_space(3))) void*)l, 16, 0, 0);
      }
    } else {
      int k0 = kt << 5;
      int r0 = tid >> 2, c = (tid & 3) << 3;
      {
        f32x4 f0 = *(const f32x4*)(agp0 + k0);
        f32x4 f1 = *(const f32x4*)(agp0 + k0 + 4);
        ushort8 u;
        u[0]=f2bf(f0[0]); u[1]=f2bf(f0[1]); u[2]=f2bf(f0[2]); u[3]=f2bf(f0[3]);
        u[4]=f2bf(f1[0]); u[5]=f2bf(f1[1]); u[6]=f2bf(f1[2]); u[7]=f2bf(f1[3]);
        *(ushort8*)&As[bi][r0][c] = u;
      }
      {
        f32x4 f0 = *(const f32x4*)(agp1 + k0);
        f32x4 f1 = *(const f32x4*)(agp1 + k0 + 4);
        ushort8 u;
        u[0]=f2bf(f0[0]); u[1]=f2bf(f0[1]); u[2]=f2bf(f0[2]); u[3]=f2bf(f0[3]);
        u[4]=f2bf(f1[0]); u[5]=f2bf(f1[1]); u[6]=f2bf(f1[2]); u[7]=f2bf(f1[3]);
        *(ushort8*)&As[bi][r0 + 64][c] = u;
      }
    }
    // B: async global->LDS from pre-packed linear tile
    const unsigned short* tb = Wt + (((size_t)(nt * 32 + kt)) << 12);
    #pragma unroll
    for (int j = 0; j < 2; ++j) {
      int chunk = wave * 2 + j;
      const unsigned short* g = tb + chunk * 512 + lane * 8;
      void* l = (void*)(&Bs[bi][0][0] + chunk * 512);
      __builtin_amdgcn_global_load_lds((__attribute__((address_space(1))) void*)(void*)g,
                                       (__attribute__((address_space(3))) void*)l, 16, 0, 0);
    }
  };

  auto compute = [&](int bi) {
    bf16x8 a[4], bb[4];
    #pragma unroll
    for (int i = 0; i < 4; ++i)
      a[i] = *(const bf16x8*)&As[bi][wm * 64 + i * 16 + (lane & 15)][(lane >> 4) << 3];
    #pragma unroll
    for (int j = 0; j < 4; ++j)
      bb[j] = *(const bf16x8*)&Bs[bi][wn * 64 + j * 16 + (lane & 15)][(lane >> 4) << 3];
    #pragma unroll
    for (int i = 0; i < 4; ++i)
      #pragma unroll
      for (int j = 0; j < 4; ++j)
        acc[i][j] = __builtin_amdgcn_mfma_f32_16x16x32_bf16(a[i], bb[j], acc[i][j], 0, 0, 0);
  };

  stage(0, 0);
  __syncthreads();
  int bi = 0;
  for (int kt = 0; kt < 31; ++kt) {
    stage(bi ^ 1, kt + 1);
    compute(bi);
    __syncthreads();
    bi ^= 1;
  }
  compute(bi);

  // epilogue: p[row] = sum_d v[d] * tanh(acc + dh[b][d]), partial over this nt
  int cb = n0 + wn * 64 + (lane & 15);
  float vv[4], dd[4];
  #pragma unroll
  for (int j = 0; j < 4; ++j) {
    int dcol = cb + j * 16;
    vv[j] = v[dcol];
    dd[j] = dh[(b << 10) + dcol];
  }
  #pragma unroll
  for (int i = 0; i < 4; ++i) {
    #pragma unroll
    for (int r = 0; r < 4; ++r) {
      float p = 0.f;
      #pragma unroll
      for (int j = 0; j < 4; ++j) {
        float x = acc[i][j][r] + dd[j];
        float e = __expf(2.0f * x);                 // tanh(x) = 1 - 2/(e^{2x}+1)
        float t = 1.0f - __fdividef(2.0f, e + 1.0f);
        p += vv[j] * t;
      }
      p += __shfl_xor(p, 1); p += __shfl_xor(p, 2);
      p += __shfl_xor(p, 4); p += __shfl_xor(p, 8);
      if ((lane & 15) == 0)
        sc[wm * 64 + i * 16 + ((lane >> 4) << 2) + r][wn] = p;
    }
  }
  __syncthreads();
  if (tid < 128) {
    int i = mt * 128 + tid;
    if (i < cb_cnt)
      pscores[((size_t)nt << 16) + (b << 11) + i] = sc[tid][0] + sc[tid][1];
  }
}

// ---------------- softmax over compacted scores; scatter weights ----------------
__global__ void softmax2_k(const float* __restrict__ ps, const int* __restrict__ rows,
                           const int* __restrict__ cnt, float* __restrict__ wout,
                           float* __restrict__ wc) {
  int b = blockIdx.x;
  int tid = threadIdx.x;
  int n = cnt[b];
  float val[8];
  float m = -INFINITY;
  #pragma unroll
  for (int ii = 0; ii < 8; ++ii) {
    int i = tid + ii * 256;
    float s = -INFINITY;
    if (i < n) {
      s = 0.f;
      #pragma unroll
      for (int nt = 0; nt < 8; ++nt) s += ps[((size_t)nt << 16) + (b << 11) + i];
    }
    val[ii] = s;
    m = fmaxf(m, s);
  }
  #pragma unroll
  for (int off = 1; off < 64; off <<= 1) m = fmaxf(m, __shfl_xor(m, off));
  __shared__ float r1[4], r2[4];
  if ((tid & 63) == 0) r1[tid >> 6] = m;
  __syncthreads();
  m = fmaxf(fmaxf(r1[0], r1[1]), fmaxf(r1[2], r1[3]));
  float ssum = 0.f;
  #pragma unroll
  for (int ii = 0; ii < 8; ++ii) { val[ii] = __expf(val[ii] - m); ssum += val[ii]; }
  #pragma unroll
  for (int off = 1; off < 64; off <<= 1) ssum += __shfl_xor(ssum, off);
  if ((tid & 63) == 0) r2[tid >> 6] = ssum;
  __syncthreads();
  ssum = r2[0] + r2[1] + r2[2] + r2[3];
  float inv = 1.0f / ssum;
  #pragma unroll
  for (int ii = 0; ii < 8; ++ii) {
    int i = tid + ii * 256;
    if (i < n) {
      float w = val[ii] * inv;
      wc[(b << 11) + i] = w;
      wout[((size_t)b << 11) + rows[(b << 11) + i]] = w;
    }
  }
}

// ---------------- context partials over compacted rows (gathered f32) ----------------
__global__ void ctx2_k(const float* __restrict__ enc, const float* __restrict__ wc,
                       const int* __restrict__ rows, const int* __restrict__ cnt,
                       float* __restrict__ cp) {
  int bb = blockIdx.x;                 // 512 = 32 b * 16 chunks(128 compacted rows)
  int b = bb >> 4, ch = bb & 15;
  int n = cnt[b];
  int i0 = ch << 7;
  __shared__ float sw[128];
  __shared__ int sr[128];
  if (threadIdx.x < 128) {
    int i = i0 + threadIdx.x;
    sw[threadIdx.x] = (i < n) ? wc[(b << 11) + i] : 0.f;
    int ic = (i < n) ? i : (n - 1);
    sr[threadIdx.x] = rows[(b << 11) + ic];
  }
  __syncthreads();
  int nv = n - i0; if (nv > 128) nv = 128; if (nv < 0) nv = 0;
  int e0 = threadIdx.x << 2;
  f32x4 acc = {0.f, 0.f, 0.f, 0.f};
  for (int s = 0; s < nv; ++s) {
    const float* base = enc + ((((size_t)(b << 11)) + sr[s]) << 10) + e0;
    f32x4 x = *(const f32x4*)base;
    float w = sw[s];
    acc[0] += w * x[0]; acc[1] += w * x[1]; acc[2] += w * x[2]; acc[3] += w * x[3];
  }
  *(f32x4*)(cp + ((size_t)bb << 10) + e0) = acc;   // always write (zeros if empty chunk)
}

__global__ void ctx_red_k(const float* __restrict__ cp, float* __restrict__ out) {
  int t = blockIdx.x * 256 + threadIdx.x;   // 32768
  int b = t >> 10, e = t & 1023;
  float a = 0.f;
  #pragma unroll
  for (int ch = 0; ch < 16; ++ch) a += cp[(((size_t)(b * 16 + ch)) << 10) + e];
  out[t] = a;
}

extern "C" void kernel_launch(void* const* d_in, const int* in_sizes, int n_in,
                              void* d_out, int out_size, void* d_ws, size_t ws_size,
                              hipStream_t stream) {
  const float* dec  = (const float*)d_in[0];
  const float* enc  = (const float*)d_in[1];
  const int*   mask = (const int*)d_in[2];
  const float* Wenc = (const float*)d_in[3];
  const float* Wdec = (const float*)d_in[4];
  const float* v    = (const float*)d_in[5];
  float* out_ctx = (float*)d_out;                 // [32][1024]
  float* out_w   = (float*)d_out + 32768;         // [32][2048]

  char* ws = (char*)d_ws;
  unsigned short* Wt = (unsigned short*)ws;                       // 2 MB   bf16 W_enc tiles
  float* dh    = (float*)(ws + (2u << 20));                       // 128 KB
  int*   rows  = (int*)(ws + (2u << 20) + (128u << 10));          // 256 KB
  float* wc    = (float*)(ws + (2u << 20) + (384u << 10));        // 256 KB
  int*   cnt   = (int*)(ws + (2u << 20) + (640u << 10));          // 4 KB
  float* pscores = (float*)(ws + (3u << 20));                     // 2 MB  [8][32][2048]
  float* cp      = (float*)(ws + (3u << 20));                     // aliases pscores (disjoint lifetime)
  unsigned short* encP = (unsigned short*)(ws + (8ull << 20));    // 128 MB bf16 packed enc tiles

  bool fast = ws_size >= (136ull << 20);

  hipLaunchKernelGGL(prep_w_k,   dim3(512), dim3(256), 0, stream, Wenc, Wt);
  hipLaunchKernelGGL(prep_dh_k,  dim3(128), dim3(256), 0, stream, dec, Wdec, dh);
  hipLaunchKernelGGL(compact_k,  dim3(32),  dim3(256), 0, stream, mask, rows, cnt, out_w);
  if (fast) {
    hipLaunchKernelGGL(pack_k,          dim3(512),  dim3(256), 0, stream, enc, rows, cnt, encP);
    hipLaunchKernelGGL(score2_k<true>,  dim3(4096), dim3(256), 0, stream, enc, encP, Wt, dh, v, rows, cnt, pscores);
  } else {
    hipLaunchKernelGGL(score2_k<false>, dim3(4096), dim3(256), 0, stream, enc, encP, Wt, dh, v, rows, cnt, pscores);
  }
  hipLaunchKernelGGL(softmax2_k, dim3(32),  dim3(256), 0, stream, pscores, rows, cnt, out_w, wc);
  hipLaunchKernelGGL(ctx2_k,     dim3(512), dim3(256), 0, stream, enc, wc, rows, cnt, cp);
  hipLaunchKernelGGL(ctx_red_k,  dim3(128), dim3(256), 0, stream, cp, out_ctx);
}